// Round 9
// baseline (521.738 us; speedup 1.0000x reference)
//
#include <hip/hip_runtime.h>
#include <math.h>

#define B_ 16
#define H_ 224
#define W_ 224
#define HP_ 226
#define WP_ 226
#define NPIX_ (B_ * H_ * W_)      /* 802816 */
#define NPAD_ (B_ * HP_ * WP_)    /* 817216 */
#define NROWS_ (B_ * H_ * 2)      /* 7168 half-rows (112 px each) */
#define NBLKC_ (NROWS_ / 4)       /* 1792 blocks, 4 waves/block */
#define MAXNORM_ 0.999f
#define MINN_ 1e-7f
#define TCL_ (1.0f - 1e-5f)
#define LCLAMP_ 3.8002012f        /* atanh(0.999) */
#define BN_EPS_ 1e-5f
#define NF_ ((float)NPIX_)

// ---------------------------------------------------------------------------
// R6-R9 dataflow flip. R1-R5 established: any "thread = pixel, 64ch in
// regs" conv kernel is pinned at 120-135us / VALUBusy 20%, independent of
// occupancy, spills, LDS tile shape, or weight residency. Root cause is the
// dataflow: every thread privately re-materializes 432 weight quads and every
// per-pixel norm forces an LDS transpose. New mapping: LANE = CHANNEL.
//  - 27 weights/lane, loaded ONCE into VGPRs (coalesced 256B loads).
//  - u0p rows staged to LDS, consumed as uniform-address broadcasts
//    (conflict-free) through a 4-column sliding register window.
//  - per-pixel 64-ch norm = 6-step shfl_xor butterfly, no transpose tile.
//  - stats: lane c accumulates channel c in 2 regs; 1 store/wave.
//  - output: lane-contiguous 256B store per pixel, zero amplification.
// R7 fix vs R6: (X##0).x parenthesization -- `0.x` lexes as one pp-number,
// so X##0.x is an invalid paste; (X##0).x splits the tokens correctly.
// R9 = R7 resubmitted verbatim (R7/R8 benches were GPUAcquisitionTimeouts;
// the theory is still untested).
// ---------------------------------------------------------------------------

// ---------------------------------------------------------------------------
// K0: x (NCHW f32) -> u0p (padded NHWC4): u0 = logmap0(projx(x)) per pixel,
// zero halo ring. atanh(t) = 0.5*log((1+t)/(1-t)) via v_log_f32.
// ---------------------------------------------------------------------------
__global__ void k0_transform(const float* __restrict__ x, float4* __restrict__ u0p) {
  int idx = blockIdx.x * 256 + threadIdx.x;
  if (idx >= NPAD_) return;
  int b = idx / (HP_ * WP_);
  int r = idx % (HP_ * WP_);
  int yp = r / WP_, xp = r % WP_;
  float4 o = make_float4(0.f, 0.f, 0.f, 0.f);
  if (yp >= 1 && yp <= H_ && xp >= 1 && xp <= W_) {
    const float* xb = x + (size_t)b * (3 * H_ * W_) + (size_t)(yp - 1) * W_ + (xp - 1);
    float v0 = xb[0];
    float v1 = xb[H_ * W_];
    float v2 = xb[2 * H_ * W_];
    // projx
    float n = sqrtf(fmaf(v0, v0, fmaf(v1, v1, v2 * v2)));
    float ncl = fmaxf(n, MINN_);
    float s = fminf(1.0f, MAXNORM_ / ncl);
    float p0 = v0 * s, p1 = v1 * s, p2 = v2 * s;
    // logmap0
    float np_ = fmaxf(sqrtf(fmaf(p0, p0, fmaf(p1, p1, p2 * p2))), MINN_);
    float t = fminf(np_, TCL_);
    float ath = 0.5f * __logf(__fdividef(1.0f + t, 1.0f - t));
    float f = __fdividef(ath, np_);
    o.x = p0 * f; o.y = p1 * f; o.z = p2 * f;
  }
  u0p[idx] = o;
}

// ---- shared conv machinery (lane = channel) -------------------------------
// column register window: col X = 3 float4 (padded rows 0,1,2)
#define DEFCOL(n) float4 n##0, n##1, n##2;
#define LDCOL(n, j) { n##0 = ub[(j)]; n##1 = ub[58 + (j)]; n##2 = ub[116 + (j)]; }
#define CPYCOL(d, s) { d##0 = s##0; d##1 = s##1; d##2 = s##2; }

// accumulate kernel-column d (taps rows 0..2, cin 0..2) of window column X
// w_[k], k = (ky*3+kx)*3+ci  (HWIO: wgt[k*64 + lane]); all indices constant.
#define C3(acc, X, d)                                                        \
  acc = fmaf((X##0).x, w_[((0 * 3 + (d)) * 3) + 0], acc);                    \
  acc = fmaf((X##0).y, w_[((0 * 3 + (d)) * 3) + 1], acc);                    \
  acc = fmaf((X##0).z, w_[((0 * 3 + (d)) * 3) + 2], acc);                    \
  acc = fmaf((X##1).x, w_[((1 * 3 + (d)) * 3) + 0], acc);                    \
  acc = fmaf((X##1).y, w_[((1 * 3 + (d)) * 3) + 1], acc);                    \
  acc = fmaf((X##1).z, w_[((1 * 3 + (d)) * 3) + 2], acc);                    \
  acc = fmaf((X##2).x, w_[((2 * 3 + (d)) * 3) + 0], acc);                    \
  acc = fmaf((X##2).y, w_[((2 * 3 + (d)) * 3) + 1], acc);                    \
  acc = fmaf((X##2).z, w_[((2 * 3 + (d)) * 3) + 2], acc);

// 64-lane butterflies (wave = 64 on gfx950)
#define BFLY1(x) {                                                           \
  x += __shfl_xor(x, 1, 64);  x += __shfl_xor(x, 2, 64);                     \
  x += __shfl_xor(x, 4, 64);  x += __shfl_xor(x, 8, 64);                     \
  x += __shfl_xor(x, 16, 64); x += __shfl_xor(x, 32, 64); }
#define BFLY2(x, y) {                                                        \
  x += __shfl_xor(x, 1, 64);  y += __shfl_xor(y, 1, 64);                     \
  x += __shfl_xor(x, 2, 64);  y += __shfl_xor(y, 2, 64);                     \
  x += __shfl_xor(x, 4, 64);  y += __shfl_xor(y, 4, 64);                     \
  x += __shfl_xor(x, 8, 64);  y += __shfl_xor(y, 8, 64);                     \
  x += __shfl_xor(x, 16, 64); y += __shfl_xor(y, 16, 64);                    \
  x += __shfl_xor(x, 32, 64); y += __shfl_xor(y, 32, 64); }

// wave/role setup shared by k1/k3: wave = half-row (112 px, 2 chunks of 56)
#define CONV_SETUP()                                                         \
  int tid = threadIdx.x, lane = tid & 63, wid = tid >> 6;                    \
  int id = blockIdx.x * 4 + wid;                                             \
  int b = id / (H_ * 2); int rem = id % (H_ * 2);                            \
  int y = rem >> 1; int hx0 = (rem & 1) * 112;                               \
  float w_[27];                                                              \
  _Pragma("unroll")                                                          \
  for (int k = 0; k < 27; k++) w_[k] = wgt[k * 64 + lane];                   \
  float bi = bias[lane];                                                     \
  const float4* ubase = u0p + ((size_t)b * HP_ + y) * WP_;                   \
  float4* ub = U[wid];

// stage one chunk: 3 padded rows x 58 cols into wave-private LDS
#define STAGE_CHUNK(c0)                                                      \
  if (lane < 58) {                                                           \
    ub[lane]       = ubase[(c0) + lane];                                     \
    ub[58 + lane]  = ubase[WP_ + (c0) + lane];                               \
    ub[116 + lane] = ubase[2 * WP_ + (c0) + lane];                           \
  }                                                                          \
  __asm__ volatile("s_waitcnt lgkmcnt(0)" ::: "memory");                     \
  __builtin_amdgcn_wave_barrier();

// ---------------------------------------------------------------------------
// K1: conv + clamp + BN statistics. Per pixel: 27 FMA, one butterfly for the
// clamp norm, 2 stat FMAs. Lane c holds channel c's (sum, sumsq) for its
// half-row; one coalesced 128-float store per wave at the end.
// ---------------------------------------------------------------------------
__global__ void __launch_bounds__(256, 4)
k1_stats(const float4* __restrict__ u0p, const float* __restrict__ wgt,
         const float* __restrict__ bias, float* __restrict__ partials) {
  __shared__ float4 U[4][176];  // 11,264 B
  CONV_SETUP()
  float s = 0.f, q = 0.f;

#define K1PX(A, B, C) {                                                      \
    float acc = bi; C3(acc, A, 0) C3(acc, B, 1) C3(acc, C, 2)                \
    float n2 = acc * acc; BFLY1(n2)                                          \
    float n = sqrtf(n2);                                                     \
    float sc = (n > LCLAMP_) ? __fdividef(LCLAMP_, n) : 1.0f;                \
    float tt = acc * sc;                                                     \
    s += tt; q = fmaf(tt, tt, q); }

#pragma unroll
  for (int ch = 0; ch < 2; ch++) {
    int c0 = hx0 + 56 * ch;
    STAGE_CHUNK(c0)
    DEFCOL(A) DEFCOL(B) DEFCOL(C) DEFCOL(D)
    LDCOL(A, 0) LDCOL(B, 1)
    for (int g = 0; g < 28; g++) {
      LDCOL(C, 2 * g + 2) LDCOL(D, 2 * g + 3)
      K1PX(A, B, C)
      K1PX(B, C, D)
      CPYCOL(A, C) CPYCOL(B, D)
    }
    __builtin_amdgcn_wave_barrier();  // reads done before next chunk's writes
  }
#undef K1PX
  partials[(size_t)id * 128 + lane] = s;
  partials[(size_t)id * 128 + 64 + lane] = q;
}

// ---------------------------------------------------------------------------
// K2: 64 blocks, one per channel. Block c reduces the sum and sumsq columns
// of partials[7168][128] and writes mean[c], rstd*gamma[c].
// ---------------------------------------------------------------------------
__global__ void k2_finalize(const float* __restrict__ partials, const float* __restrict__ gamma,
                            float* __restrict__ stats) {
  int c = blockIdx.x;      // 0..63
  int t = threadIdx.x;     // 256 threads
  float s = 0.f, q = 0.f;
  for (int i = t; i < NROWS_; i += 256) {
    s += partials[(size_t)i * 128 + c];
    q += partials[(size_t)i * 128 + 64 + c];
  }
  __shared__ float ls[256], lq[256];
  ls[t] = s; lq[t] = q;
  __syncthreads();
#pragma unroll
  for (int off = 128; off > 0; off >>= 1) {
    if (t < off) { ls[t] += ls[t + off]; lq[t] += lq[t + off]; }
    __syncthreads();
  }
  if (t == 0) {
    float mean = ls[0] / NF_;
    float msq  = lq[0] / NF_;
    float var = msq - mean * mean;            // jnp.var (ddof=0)
    stats[c] = mean;
    stats[64 + c] = gamma[c] / sqrtf(var + BN_EPS_);
  }
}

// ---------------------------------------------------------------------------
// K3: conv + clamp + BN + relu + expmap0(+projx) + store. Per pixel: 27 FMA,
// clamp butterfly, BN (lane-resident mean/rg/beta), paired butterfly for
// (sum u3^2, sum relu(u3)^2), per-pixel scalar tail computed redundantly on
// all lanes, then out[px*64 + lane] = g*relu(u3): one contiguous 256B store
// per pixel (2 full cache lines, zero write amplification).
// ---------------------------------------------------------------------------
__global__ void __launch_bounds__(256, 4)
k3_final(const float4* __restrict__ u0p, const float* __restrict__ wgt,
         const float* __restrict__ bias, const float* __restrict__ stats,
         const float* __restrict__ beta, float* __restrict__ out) {
  __shared__ float4 U[4][176];  // 11,264 B
  CONV_SETUP()
  float mn = stats[lane], rgv = stats[64 + lane];
  float bt = beta[lane];

#define K3PX(A, B, C, px) {                                                  \
    float acc = bi; C3(acc, A, 0) C3(acc, B, 1) C3(acc, C, 2)                \
    float n2 = acc * acc; BFLY1(n2)                                          \
    float n = sqrtf(n2);                                                     \
    float sc = (n > LCLAMP_) ? __fdividef(LCLAMP_, n) : 1.0f;                \
    float u3 = (acc * sc - mn) * rgv + bt;                                   \
    float a2 = u3 * u3;                                                      \
    float rl = fmaxf(u3, 0.f);                                               \
    float r2 = rl * rl;                                                      \
    BFLY2(a2, r2)                                                            \
    float nv = sqrtf(a2);                                                    \
    float sv = (nv > LCLAMP_) ? __fdividef(LCLAMP_, nv) : 1.0f;              \
    float nw = fmaxf(sv * sqrtf(r2), MINN_);                                 \
    float e2 = __expf(2.0f * nw);                                            \
    float th = 1.0f - __fdividef(2.0f, e2 + 1.0f);                           \
    float se = __fdividef(th, nw);                                           \
    float clip = fminf(1.0f, MAXNORM_ / fmaxf(th, MINN_));                   \
    float g = se * clip * sv;                                                \
    obase[(size_t)(px) * 64 + lane] = rl * g; }

#pragma unroll
  for (int ch = 0; ch < 2; ch++) {
    int c0 = hx0 + 56 * ch;
    STAGE_CHUNK(c0)
    float* obase = out + ((size_t)((b * H_ + y) * W_) + hx0 + 56 * ch) * 64;
    DEFCOL(A) DEFCOL(B) DEFCOL(C) DEFCOL(D)
    LDCOL(A, 0) LDCOL(B, 1)
    for (int g2 = 0; g2 < 28; g2++) {
      LDCOL(C, 2 * g2 + 2) LDCOL(D, 2 * g2 + 3)
      K3PX(A, B, C, 2 * g2)
      K3PX(B, C, D, 2 * g2 + 1)
      CPYCOL(A, C) CPYCOL(B, D)
    }
    __builtin_amdgcn_wave_barrier();
  }
#undef K3PX
}

// ---------------------------------------------------------------------------
extern "C" void kernel_launch(void* const* d_in, const int* in_sizes, int n_in,
                              void* d_out, int out_size, void* d_ws, size_t ws_size,
                              hipStream_t stream) {
  const float* x     = (const float*)d_in[0];  // [16,3,224,224]
  const float* wgt   = (const float*)d_in[1];  // [3,3,3,64] HWIO
  const float* bias  = (const float*)d_in[2];  // [64]
  const float* gamma = (const float*)d_in[3];  // [64]
  const float* beta  = (const float*)d_in[4];  // [64]
  float* out = (float*)d_out;                  // [16,224,224,64]

  char* ws = (char*)d_ws;
  float4* u0p      = (float4*)ws;                                           // 13,075,456 B
  float*  partials = (float*)(ws + (size_t)NPAD_ * 16);                     //  3,670,016 B
  float*  stats    = (float*)(ws + (size_t)NPAD_ * 16 + (size_t)NROWS_ * 128 * 4); // 512 B

  hipLaunchKernelGGL(k0_transform, dim3((NPAD_ + 255) / 256), dim3(256), 0, stream, x, u0p);
  hipLaunchKernelGGL(k1_stats,     dim3(NBLKC_),              dim3(256), 0, stream, u0p, wgt, bias, partials);
  hipLaunchKernelGGL(k2_finalize,  dim3(64),                  dim3(256), 0, stream, partials, gamma, stats);
  hipLaunchKernelGGL(k3_final,     dim3(NBLKC_),              dim3(256), 0, stream, u0p, wgt, bias, stats, beta, out);
}